// Round 13
// baseline (393.664 us; speedup 1.0000x reference)
//
#include <hip/hip_runtime.h>
#include <stdint.h>

// BConv2d via MFMA i8 implicit GEMM (R10-verified core + fixed-budget pipeline).
// out = conv2d(sign(x), sign(w), pad=1) + b ; N=32, Cin=256, H=W=56, Cout=256, K=3.
//
// sign as i8 {+1,-1}, zero padding as i8 0 (exact, no border correction).
// conv = 9 tap-shifted GEMMs, K=256, i32 acc via v_mfma_i32_32x32x32_i8.
// C/D layout: col=lane&31, row=(reg&3)+8*(reg>>2)+4*(lane>>5) (verified R8-R10).
//
// R12 lesson: VGPR_Count stuck at 64 for 4 rounds -- the unrolled cb passes
// gave each pass its own 32-AGPR acc set (64 total), pinning arch VGPRs at
// 64 under the (512,4) 128-reg unified cap; no room to schedule loads ahead.
// R13: (1) #pragma unroll 1 on cb -> ONE acc set (32 AGPR) -> ~96 arch VGPRs;
// (2) copy-free 2-stage register pipeline over the 24 (dw,c8) groups: two
// named fragment sets alternate in a hand-unrolled pair loop (all static).

#define NBATCH 32
#define CIN    256
#define COUT   256
#define HH     56
#define WW     56
#define HW     (HH*WW)          // 3136
#define NPIX   (NBATCH*HW)      // 100352

#define PW    58                // padded bit-image width/height
#define PROW  (PW*8)            // 464 words per padded row
#define PIMG  (PW*PW*8)         // 26912 words per padded image

#define XP_BYTES  ((size_t)NBATCH * PIMG * 4)  // 3,444,736 (16-aligned)
#define WQ_BYTES  ((size_t)9 * 8 * 256 * 32)   // 589,824

typedef int i32x4  __attribute__((ext_vector_type(4)));
typedef int i32x16 __attribute__((ext_vector_type(16)));

// ---- pack x bits: wave handles 64 channels (2 words) for 64 pixels
__global__ __launch_bounds__(256) void pack_x_kernel(
    const float* __restrict__ x, uint32_t* __restrict__ xp)
{
    int lane = threadIdx.x & 63;
    int wv   = threadIdx.x >> 6;               // 0..3 -> channel group
    int pix  = blockIdx.x * 64 + lane;         // 1568 blocks * 64 == NPIX
    int n  = pix / HW;
    int hw = pix - n * HW;
    int h  = hw / WW;
    int w_ = hw - h * WW;
    const float* xb = x + ((size_t)n * CIN + (size_t)wv * 64) * HW + hw;

    uint32_t w0 = 0, w1 = 0;
    #pragma unroll
    for (int j = 0; j < 32; ++j) {
        w0 |= (xb[(size_t)j * HW]        >= 0.0f ? 1u : 0u) << j;
        w1 |= (xb[(size_t)(j + 32) * HW] >= 0.0f ? 1u : 0u) << j;
    }
    uint32_t* dst = xp + (size_t)n * PIMG + (size_t)(h + 1) * PROW
                       + (size_t)(w_ + 1) * 8 + wv * 2;
    *(uint2*)dst = make_uint2(w0, w1);
}

// ---- pack w -> i8 {+1,-1}, layout wq[t][c8][co][slot], slot = ci&31
__global__ __launch_bounds__(256) void pack_w2_kernel(
    const float* __restrict__ w, int8_t* __restrict__ wq)
{
    int co = blockIdx.x, ci = threadIdx.x;
    const float* wb = w + ((size_t)co * CIN + ci) * 9;
    int c8 = ci >> 5, s = ci & 31;
    #pragma unroll
    for (int t = 0; t < 9; ++t) {
        wq[((size_t)(t * 8 + c8) * 256 + co) * 32 + s] =
            (wb[t] >= 0.0f) ? (int8_t)1 : (int8_t)-1;
    }
}

// ---- conv
#define LOADG(gi, A0, A1, A2, B0, B1, B2, B3) { \
    const int dw_ = (gi) >> 3, c8_ = (gi) & 7; \
    const int col_ = l31 + cb * 32 + dw_; \
    const int sw_ = (col_ & 15) << 4; \
    const char* xc_ = xtb + (col_ << 8); \
    const int sx_ = ((c8_ << 5) + hi16) ^ sw_; \
    B0 = *(const i32x4*)(xc_ + ((0 * 66) << 8) + sx_); \
    B1 = *(const i32x4*)(xc_ + ((1 * 66) << 8) + sx_); \
    B2 = *(const i32x4*)(xc_ + ((2 * 66) << 8) + sx_); \
    B3 = *(const i32x4*)(xc_ + ((3 * 66) << 8) + sx_); \
    const char* wa_ = wql + (size_t)((dw_ * 8 + c8_)) * 8192; \
    A0 = *(const i32x4*)(wa_); \
    A1 = *(const i32x4*)(wa_ + 196608); \
    A2 = *(const i32x4*)(wa_ + 393216); }

#define MFMA6(A0, A1, A2, B0, B1, B2, B3) \
    accA = __builtin_amdgcn_mfma_i32_32x32x32_i8(A0, B0, accA, 0, 0, 0); \
    accB = __builtin_amdgcn_mfma_i32_32x32x32_i8(A0, B1, accB, 0, 0, 0); \
    accA = __builtin_amdgcn_mfma_i32_32x32x32_i8(A1, B1, accA, 0, 0, 0); \
    accB = __builtin_amdgcn_mfma_i32_32x32x32_i8(A1, B2, accB, 0, 0, 0); \
    accA = __builtin_amdgcn_mfma_i32_32x32x32_i8(A2, B2, accA, 0, 0, 0); \
    accB = __builtin_amdgcn_mfma_i32_32x32x32_i8(A2, B3, accB, 0, 0, 0);

__global__ __launch_bounds__(512, 4) void bconv_kernel(
    const uint32_t* __restrict__ xp, const int8_t* __restrict__ wq,
    const float* __restrict__ bias, float* __restrict__ out)
{
    __shared__ __align__(16) int8_t xt[4][66][256];   // 67,584 B
    __shared__ float bsh[256];

    int bx = blockIdx.x;               // 0..895
    int n  = bx / 28;
    int hb = bx - n * 28;
    int h  = hb * 2;                   // output rows h, h+1
    int tid = threadIdx.x, lane = tid & 63, wv = tid >> 6;

    if (tid < 256) bsh[tid] = bias[tid];

    // expand packed sign bits -> i8 (+1/-1); borders & cols>=58 -> 0
    const uint32_t* xpb = xp + (size_t)n * PIMG;
    for (int e = tid; e < 4 * 66 * 64; e += 512) {   // 33 iters exactly
        int pr  = e / (66 * 64);
        int rem = e - pr * (66 * 64);
        int col = rem >> 6;
        int d   = rem & 63;            // output dword = 4 ci
        int prg = h + pr;              // padded global row
        bool val = (prg >= 1) & (prg <= 56) & (col >= 1) & (col <= 56);
        uint32_t wvv = 0;
        if (val) wvv = xpb[(size_t)prg * PROW + col * 8 + (d >> 3)];
        uint32_t nib = (wvv >> ((d & 7) * 4)) & 0xFu;
        uint32_t sp  = (nib * 0x00204081u) & 0x01010101u;   // bit k -> byte k
        uint32_t o   = val ? __builtin_amdgcn_perm(0u, 0x000001FFu, sp) : 0u;
        uint32_t ba  = (uint32_t)((((pr * 66 + col) << 8) | (d << 2))
                                  ^ ((col & 15) << 4));
        *(uint32_t*)((char*)&xt[0][0][0] + ba) = o;
    }
    __syncthreads();

    int l31  = lane & 31;
    int hi16 = (lane >> 5) << 4;
    const char* wql = (const char*)wq + (size_t)(wv * 32 + l31) * 32 + hi16;
    const char* xtb = (const char*)&xt[0][0][0];

    #pragma unroll 1
    for (int cb = 0; cb < 2; ++cb) {
        i32x16 accA = {0}, accB = {0};     // output rows h, h+1
        i32x4 a0, a1, a2, b0, b1, b2, b3;  // pipeline set 0
        i32x4 c0, c1, c2, d0, d1, d2, d3;  // pipeline set 1

        LOADG(0, a0, a1, a2, b0, b1, b2, b3)
        #pragma unroll
        for (int gp = 0; gp < 12; ++gp) {
            LOADG(2 * gp + 1, c0, c1, c2, d0, d1, d2, d3)
            MFMA6(a0, a1, a2, b0, b1, b2, b3)
            if (gp < 11) { LOADG(2 * gp + 2, a0, a1, a2, b0, b1, b2, b3) }
            MFMA6(c0, c1, c2, d0, d1, d2, d3)
        }

        // epilogue: C col=pixel(lane&31 within colblk), row=(r&3)+8*(r>>2)+4*(lane>>5)
        int pix = cb * 32 + l31;
        if (pix < WW) {
            float* op = out + (size_t)n * COUT * HW + (size_t)h * WW + pix;
            #pragma unroll
            for (int r = 0; r < 16; ++r) {
                int row = (r & 3) + 8 * (r >> 2) + ((lane >> 5) << 2);
                int co  = (wv << 5) + row;
                float bb = bsh[co];
                op[(size_t)co * HW]      = (float)accA[r] + bb;
                op[(size_t)co * HW + WW] = (float)accB[r] + bb;
            }
        }
    }
}

extern "C" void kernel_launch(void* const* d_in, const int* in_sizes, int n_in,
                              void* d_out, int out_size, void* d_ws, size_t ws_size,
                              hipStream_t stream) {
    const float* x = (const float*)d_in[0];
    const float* w = (const float*)d_in[1];
    const float* b = (const float*)d_in[2];
    float* out = (float*)d_out;

    uint32_t* xp = (uint32_t*)d_ws;
    int8_t*   wq = (int8_t*)((char*)d_ws + XP_BYTES);

    pack_x_kernel<<<NPIX / 64, 256, 0, stream>>>(x, xp);
    pack_w2_kernel<<<COUT, 256, 0, stream>>>(w, wq);

    bconv_kernel<<<NBATCH * (HH / 2), 512, 0, stream>>>(xp, wq, b, out);
}

// Round 14
// 108.730 us; speedup vs baseline: 3.6206x; 3.6206x over previous
//
#include <hip/hip_runtime.h>
#include <stdint.h>

// BConv2d via MFMA i8 implicit GEMM (R10-verified core, ILP-over-TLP regime).
// out = conv2d(sign(x), sign(w), pad=1) + b ; N=32, Cin=256, H=W=56, Cout=256, K=3.
//
// sign as i8 {+1,-1}, zero padding as i8 0 (exact, no border correction).
// conv = 9 tap-shifted GEMMs, K=256, i32 acc via v_mfma_i32_32x32x32_i8.
// C/D layout: col=lane&31, row=(reg&3)+8*(reg>>2)+4*(lane>>5) (verified R8-R10).
//
// R8-R13 lesson: at launch_bounds(512,4) each wave has 128 unified regs;
// acc+operands+addressing consume it all -> no ILP possible, and 4 waves/SIMD
// don't cover latency (all pipes ~30% busy). R14 trades occupancy for regs:
// (512,2) -> 256-reg cap, 2 waves/SIMD, 1 block/CU;
// per-dw A-BURST (24 fragments -> 96 VGPRs, one L2 round-trip per dw) +
// 2-deep B prefetch (alternating named sets). aa[][] only ever indexed by
// fully-unrolled loop vars (static -> registers, rule #20).

#define NBATCH 32
#define CIN    256
#define COUT   256
#define HH     56
#define WW     56
#define HW     (HH*WW)          // 3136
#define NPIX   (NBATCH*HW)      // 100352

#define PW    58                // padded bit-image width/height
#define PROW  (PW*8)            // 464 words per padded row
#define PIMG  (PW*PW*8)         // 26912 words per padded image

#define XP_BYTES  ((size_t)NBATCH * PIMG * 4)  // 3,444,736 (16-aligned)
#define WQ_BYTES  ((size_t)9 * 8 * 256 * 32)   // 589,824

typedef int i32x4  __attribute__((ext_vector_type(4)));
typedef int i32x16 __attribute__((ext_vector_type(16)));

// ---- pack x bits: wave handles 64 channels (2 words) for 64 pixels
__global__ __launch_bounds__(256) void pack_x_kernel(
    const float* __restrict__ x, uint32_t* __restrict__ xp)
{
    int lane = threadIdx.x & 63;
    int wv   = threadIdx.x >> 6;               // 0..3 -> channel group
    int pix  = blockIdx.x * 64 + lane;         // 1568 blocks * 64 == NPIX
    int n  = pix / HW;
    int hw = pix - n * HW;
    int h  = hw / WW;
    int w_ = hw - h * WW;
    const float* xb = x + ((size_t)n * CIN + (size_t)wv * 64) * HW + hw;

    uint32_t w0 = 0, w1 = 0;
    #pragma unroll
    for (int j = 0; j < 32; ++j) {
        w0 |= (xb[(size_t)j * HW]        >= 0.0f ? 1u : 0u) << j;
        w1 |= (xb[(size_t)(j + 32) * HW] >= 0.0f ? 1u : 0u) << j;
    }
    uint32_t* dst = xp + (size_t)n * PIMG + (size_t)(h + 1) * PROW
                       + (size_t)(w_ + 1) * 8 + wv * 2;
    *(uint2*)dst = make_uint2(w0, w1);
}

// ---- pack w -> i8 {+1,-1}, layout wq[t][c8][co][slot], slot = ci&31
__global__ __launch_bounds__(256) void pack_w2_kernel(
    const float* __restrict__ w, int8_t* __restrict__ wq)
{
    int co = blockIdx.x, ci = threadIdx.x;
    const float* wb = w + ((size_t)co * CIN + ci) * 9;
    int c8 = ci >> 5, s = ci & 31;
    #pragma unroll
    for (int t = 0; t < 9; ++t) {
        wq[((size_t)(t * 8 + c8) * 256 + co) * 32 + s] =
            (wb[t] >= 0.0f) ? (int8_t)1 : (int8_t)-1;
    }
}

// ---- conv
#define LOADB(c8x, B0, B1, B2, B3) { \
    const int sx_ = (((c8x) << 5) + hi16) ^ sw; \
    B0 = *(const i32x4*)(xc + ((0 * 66) << 8) + sx_); \
    B1 = *(const i32x4*)(xc + ((1 * 66) << 8) + sx_); \
    B2 = *(const i32x4*)(xc + ((2 * 66) << 8) + sx_); \
    B3 = *(const i32x4*)(xc + ((3 * 66) << 8) + sx_); }

#define MFMA6(A0, A1, A2, B0, B1, B2, B3) \
    accA = __builtin_amdgcn_mfma_i32_32x32x32_i8(A0, B0, accA, 0, 0, 0); \
    accB = __builtin_amdgcn_mfma_i32_32x32x32_i8(A0, B1, accB, 0, 0, 0); \
    accA = __builtin_amdgcn_mfma_i32_32x32x32_i8(A1, B1, accA, 0, 0, 0); \
    accB = __builtin_amdgcn_mfma_i32_32x32x32_i8(A1, B2, accB, 0, 0, 0); \
    accA = __builtin_amdgcn_mfma_i32_32x32x32_i8(A2, B2, accA, 0, 0, 0); \
    accB = __builtin_amdgcn_mfma_i32_32x32x32_i8(A2, B3, accB, 0, 0, 0);

__global__ __launch_bounds__(512, 2) void bconv_kernel(
    const uint32_t* __restrict__ xp, const int8_t* __restrict__ wq,
    const float* __restrict__ bias, float* __restrict__ out)
{
    __shared__ __align__(16) int8_t xt[4][66][256];   // 67,584 B
    __shared__ float bsh[256];

    int bx = blockIdx.x;               // 0..895
    int n  = bx / 28;
    int hb = bx - n * 28;
    int h  = hb * 2;                   // output rows h, h+1
    int tid = threadIdx.x, lane = tid & 63, wv = tid >> 6;

    if (tid < 256) bsh[tid] = bias[tid];

    // expand packed sign bits -> i8 (+1/-1); borders & cols>=58 -> 0
    const uint32_t* xpb = xp + (size_t)n * PIMG;
    for (int e = tid; e < 4 * 66 * 64; e += 512) {   // 33 iters exactly
        int pr  = e / (66 * 64);
        int rem = e - pr * (66 * 64);
        int col = rem >> 6;
        int d   = rem & 63;            // output dword = 4 ci
        int prg = h + pr;              // padded global row
        bool val = (prg >= 1) & (prg <= 56) & (col >= 1) & (col <= 56);
        uint32_t wvv = 0;
        if (val) wvv = xpb[(size_t)prg * PROW + col * 8 + (d >> 3)];
        uint32_t nib = (wvv >> ((d & 7) * 4)) & 0xFu;
        uint32_t sp  = (nib * 0x00204081u) & 0x01010101u;   // bit k -> byte k
        uint32_t o   = val ? __builtin_amdgcn_perm(0u, 0x000001FFu, sp) : 0u;
        uint32_t ba  = (uint32_t)((((pr * 66 + col) << 8) | (d << 2))
                                  ^ ((col & 15) << 4));
        *(uint32_t*)((char*)&xt[0][0][0] + ba) = o;
    }
    __syncthreads();

    int l31  = lane & 31;
    int hi16 = (lane >> 5) << 4;
    const char* wql = (const char*)wq + (size_t)(wv * 32 + l31) * 32 + hi16;
    const char* xtb = (const char*)&xt[0][0][0];

    #pragma unroll 1
    for (int cb = 0; cb < 2; ++cb) {
        i32x16 accA = {0}, accB = {0};     // output rows h, h+1

        #pragma unroll 1
        for (int dw = 0; dw < 3; ++dw) {
            int col = l31 + cb * 32 + dw;
            int sw  = (col & 15) << 4;
            const char* xc = xtb + (col << 8);

            // A-BURST: all 24 fragments of this dw in one shot (96 VGPRs)
            i32x4 aa[8][3];
            #pragma unroll
            for (int c8 = 0; c8 < 8; ++c8) {
                const char* wa = wql + (size_t)((dw * 8 + c8)) * 8192;
                aa[c8][0] = *(const i32x4*)(wa);
                aa[c8][1] = *(const i32x4*)(wa + 196608);
                aa[c8][2] = *(const i32x4*)(wa + 393216);
            }

            // 2-deep B prefetch over c8 (alternating named sets)
            i32x4 b0, b1, b2, b3, d0, d1, d2, d3;
            LOADB(0, b0, b1, b2, b3)
            #pragma unroll
            for (int gp = 0; gp < 4; ++gp) {
                LOADB(2 * gp + 1, d0, d1, d2, d3)
                MFMA6(aa[2 * gp][0], aa[2 * gp][1], aa[2 * gp][2], b0, b1, b2, b3)
                if (gp < 3) { LOADB(2 * gp + 2, b0, b1, b2, b3) }
                MFMA6(aa[2 * gp + 1][0], aa[2 * gp + 1][1], aa[2 * gp + 1][2], d0, d1, d2, d3)
            }
        }

        // epilogue: C col=pixel(lane&31 within colblk), row=(r&3)+8*(r>>2)+4*(lane>>5)
        int pix = cb * 32 + l31;
        if (pix < WW) {
            float* op = out + (size_t)n * COUT * HW + (size_t)h * WW + pix;
            #pragma unroll
            for (int r = 0; r < 16; ++r) {
                int row = (r & 3) + 8 * (r >> 2) + ((lane >> 5) << 2);
                int co  = (wv << 5) + row;
                float bb = bsh[co];
                op[(size_t)co * HW]      = (float)accA[r] + bb;
                op[(size_t)co * HW + WW] = (float)accB[r] + bb;
            }
        }
    }
}

extern "C" void kernel_launch(void* const* d_in, const int* in_sizes, int n_in,
                              void* d_out, int out_size, void* d_ws, size_t ws_size,
                              hipStream_t stream) {
    const float* x = (const float*)d_in[0];
    const float* w = (const float*)d_in[1];
    const float* b = (const float*)d_in[2];
    float* out = (float*)d_out;

    uint32_t* xp = (uint32_t*)d_ws;
    int8_t*   wq = (int8_t*)((char*)d_ws + XP_BYTES);

    pack_x_kernel<<<NPIX / 64, 256, 0, stream>>>(x, xp);
    pack_w2_kernel<<<COUT, 256, 0, stream>>>(w, wq);

    bconv_kernel<<<NBATCH * (HH / 2), 512, 0, stream>>>(xp, wq, b, out);
}